// Round 1
// baseline (1158.566 us; speedup 1.0000x reference)
//
#include <hip/hip_runtime.h>

#define NNODES 100000
#define NEDGES 1600000
#define NF 64
#define NH 64
#define NC 16

// ---------------- degree + dst histogram ----------------
__global__ __launch_bounds__(256) void deg_hist_k(const int* __restrict__ src, const int* __restrict__ dst,
                                                  const float* __restrict__ ew,
                                                  float* __restrict__ deg, int* __restrict__ cnt) {
    int e = blockIdx.x * 256 + threadIdx.x;
    if (e >= NEDGES) return;
    __hip_atomic_fetch_add(&deg[src[e]], ew[e], __ATOMIC_RELAXED, __HIP_MEMORY_SCOPE_AGENT);
    __hip_atomic_fetch_add(&cnt[dst[e]], 1, __ATOMIC_RELAXED, __HIP_MEMORY_SCOPE_AGENT);
}

__global__ __launch_bounds__(256) void dinv_k(const float* __restrict__ deg, float* __restrict__ dinv) {
    int n = blockIdx.x * 256 + threadIdx.x;
    if (n >= NNODES) return;
    float d = deg[n];
    dinv[n] = (d > 0.f) ? rsqrtf(fmaxf(d, 1e-12f)) : 0.f;
}

// ---------------- exclusive scan (3-kernel) ----------------
__global__ __launch_bounds__(256) void scan1_k(const int* __restrict__ cnt, int* __restrict__ scanned,
                                               int* __restrict__ bsums, int n) {
    __shared__ int sm[256];
    int tid = threadIdx.x;
    int i = blockIdx.x * 256 + tid;
    int v = (i < n) ? cnt[i] : 0;
    sm[tid] = v;
    __syncthreads();
    #pragma unroll
    for (int off = 1; off < 256; off <<= 1) {
        int t = (tid >= off) ? sm[tid - off] : 0;
        __syncthreads();
        if (tid >= off) sm[tid] += t;
        __syncthreads();
    }
    if (i < n) scanned[i] = sm[tid] - v;          // exclusive
    if (tid == 255) bsums[blockIdx.x] = sm[255];  // block total
}

__global__ void scan2_k(int* bsums, int nb) {
    if (threadIdx.x == 0 && blockIdx.x == 0) {
        int run = 0;
        for (int i = 0; i < nb; i++) { int t = bsums[i]; bsums[i] = run; run += t; }
    }
}

__global__ __launch_bounds__(256) void scan3_k(const int* __restrict__ scanned, const int* __restrict__ bsums,
                                               int* __restrict__ rowptr, int* __restrict__ fillp, int n, int e) {
    int i = blockIdx.x * 256 + threadIdx.x;
    if (i < n) {
        int r = scanned[i] + bsums[blockIdx.x];
        rowptr[i] = r;
        fillp[i] = r;
    }
    if (i == 0) rowptr[n] = e;
}

// ---------------- CSR fill (by dst) with normalized weights ----------------
__global__ __launch_bounds__(256) void fill_k(const int* __restrict__ src, const int* __restrict__ dst,
                                              const float* __restrict__ ew, const float* __restrict__ dinv,
                                              int* __restrict__ fillp, int* __restrict__ csr_src,
                                              float* __restrict__ csr_w) {
    int e = blockIdx.x * 256 + threadIdx.x;
    if (e >= NEDGES) return;
    int s = src[e], d = dst[e];
    float nw = -dinv[s] * ew[e] * dinv[d];
    int pos = atomicAdd(&fillp[d], 1);
    csr_src[pos] = s;
    csr_w[pos] = nw;
}

// ---------------- layer 1: gather + fused dense (64->64) + relu ----------------
// one wave per node; 4 nodes per 256-thread block
__global__ __launch_bounds__(256) void layer1_k(const float* __restrict__ feat,
                                                const int* __restrict__ rowptr,
                                                const int* __restrict__ csr_src, const float* __restrict__ csr_w,
                                                const float* __restrict__ W0, const float* __restrict__ W1,
                                                const float* __restrict__ b, float* __restrict__ hout) {
    __shared__ float tx[4][128];
    int wid = threadIdx.x >> 6;
    int lane = threadIdx.x & 63;
    int n = blockIdx.x * 4 + wid;   // grid = 25000 -> exactly NNODES

    // register-hoist the two weight columns for this lane (128 VGPRs)
    float w0[64], w1[64];
    #pragma unroll
    for (int d = 0; d < 64; d++) { w0[d] = W0[d * 64 + lane]; w1[d] = W1[d * 64 + lane]; }

    float tx0 = feat[n * 64 + lane];
    float acc = 0.f;
    int rs = rowptr[n], re = rowptr[n + 1];
    for (int i = rs; i < re; i++) {
        int s = csr_src[i];
        float w = csr_w[i];
        acc = fmaf(w, feat[s * 64 + lane], acc);
    }
    tx[wid][lane] = tx0;
    tx[wid][64 + lane] = acc;
    __syncthreads();

    float hj = b[lane];
    const float4* tp = (const float4*)tx[wid];
    #pragma unroll
    for (int q = 0; q < 16; q++) {
        float4 a = tp[q];
        hj = fmaf(a.x, w0[4 * q + 0], hj);
        hj = fmaf(a.y, w0[4 * q + 1], hj);
        hj = fmaf(a.z, w0[4 * q + 2], hj);
        hj = fmaf(a.w, w0[4 * q + 3], hj);
    }
    #pragma unroll
    for (int q = 0; q < 16; q++) {
        float4 a = tp[16 + q];
        hj = fmaf(a.x, w1[4 * q + 0], hj);
        hj = fmaf(a.y, w1[4 * q + 1], hj);
        hj = fmaf(a.z, w1[4 * q + 2], hj);
        hj = fmaf(a.w, w1[4 * q + 3], hj);
    }
    hout[n * 64 + lane] = fmaxf(hj, 0.f);
}

// ---------------- layer 2: gather + fused dense (64->16) + log_softmax ----------------
__global__ __launch_bounds__(256) void layer2_k(const float* __restrict__ hin,
                                                const int* __restrict__ rowptr,
                                                const int* __restrict__ csr_src, const float* __restrict__ csr_w,
                                                const float* __restrict__ W0, const float* __restrict__ W1,
                                                const float* __restrict__ b, float* __restrict__ out) {
    __shared__ float tx[4][128];
    int wid = threadIdx.x >> 6;
    int lane = threadIdx.x & 63;
    int n = blockIdx.x * 4 + wid;

    float tx0 = hin[n * 64 + lane];
    float acc = 0.f;
    int rs = rowptr[n], re = rowptr[n + 1];
    for (int i = rs; i < re; i++) {
        int s = csr_src[i];
        float w = csr_w[i];
        acc = fmaf(w, hin[s * 64 + lane], acc);
    }
    tx[wid][lane] = tx0;
    tx[wid][64 + lane] = acc;
    __syncthreads();

    int j = lane & 15;
    int g = lane >> 4;   // 4 groups of 16 lanes; group g covers d in [16g, 16g+16)
    float p = 0.f;
    #pragma unroll
    for (int i = 0; i < 16; i++) {
        int d = g * 16 + i;
        p = fmaf(tx[wid][d],      W0[d * 16 + j], p);
        p = fmaf(tx[wid][64 + d], W1[d * 16 + j], p);
    }
    // reduce partials over the 4 groups
    p += __shfl_xor(p, 16, 64);
    p += __shfl_xor(p, 32, 64);
    float oc = p + b[j];

    // log_softmax over the 16 classes (within each 16-lane group; all groups hold full vector)
    float m = oc;
    #pragma unroll
    for (int mk = 1; mk < 16; mk <<= 1) m = fmaxf(m, __shfl_xor(m, mk, 64));
    float ex = expf(oc - m);
    float s = ex;
    #pragma unroll
    for (int mk = 1; mk < 16; mk <<= 1) s += __shfl_xor(s, mk, 64);
    float r = oc - m - logf(s);
    if (g == 0) out[n * 16 + j] = r;
}

extern "C" void kernel_launch(void* const* d_in, const int* in_sizes, int n_in,
                              void* d_out, int out_size, void* d_ws, size_t ws_size,
                              hipStream_t stream) {
    const float* feat = (const float*)d_in[0];
    const int*   eidx = (const int*)d_in[1];
    const float* ew   = (const float*)d_in[2];
    const float* W1_0 = (const float*)d_in[3];
    const float* W1_1 = (const float*)d_in[4];
    const float* b1   = (const float*)d_in[5];
    const float* W2_0 = (const float*)d_in[6];
    const float* W2_1 = (const float*)d_in[7];
    const float* b2   = (const float*)d_in[8];
    float* out = (float*)d_out;

    const int* srcv = eidx;            // edge_index[0]
    const int* dstv = eidx + NEDGES;   // edge_index[1]

    // workspace carve (all 4-byte elements)
    float* deg     = (float*)d_ws;                 // N
    float* dinv    = deg + NNODES;                 // N
    int*   cnt     = (int*)(dinv + NNODES);        // N
    int*   scanned = cnt + NNODES;                 // N
    int*   rowptr  = scanned + NNODES;             // N+1
    int*   fillp   = rowptr + NNODES + 1;          // N
    int*   bsums   = fillp + NNODES;               // 512
    int*   csr_src = bsums + 512;                  // E
    float* csr_w   = (float*)(csr_src + NEDGES);   // E
    float* hbuf    = csr_w + NEDGES;               // N*64

    hipMemsetAsync(deg, 0, NNODES * sizeof(float), stream);
    hipMemsetAsync(cnt, 0, NNODES * sizeof(int), stream);

    const int EB = (NEDGES + 255) / 256;     // 6250
    const int NB = (NNODES + 255) / 256;     // 391

    deg_hist_k<<<EB, 256, 0, stream>>>(srcv, dstv, ew, deg, cnt);
    dinv_k<<<NB, 256, 0, stream>>>(deg, dinv);
    scan1_k<<<NB, 256, 0, stream>>>(cnt, scanned, bsums, NNODES);
    scan2_k<<<1, 64, 0, stream>>>(bsums, NB);
    scan3_k<<<NB, 256, 0, stream>>>(scanned, bsums, rowptr, fillp, NNODES, NEDGES);
    fill_k<<<EB, 256, 0, stream>>>(srcv, dstv, ew, dinv, fillp, csr_src, csr_w);

    layer1_k<<<NNODES / 4, 256, 0, stream>>>(feat, rowptr, csr_src, csr_w, W1_0, W1_1, b1, hbuf);
    layer2_k<<<NNODES / 4, 256, 0, stream>>>(hbuf, rowptr, csr_src, csr_w, W2_0, W2_1, b2, out);
}

// Round 2
// 500.428 us; speedup vs baseline: 2.3152x; 2.3152x over previous
//
#include <hip/hip_runtime.h>

#define NNODES 100000
#define NEDGES 1600000

__device__ __forceinline__ float asf(int v) { return __int_as_float(v); }

// ---------------- degree + dst histogram ----------------
__global__ __launch_bounds__(256) void deg_hist_k(const int* __restrict__ src, const int* __restrict__ dst,
                                                  const float* __restrict__ ew,
                                                  float* __restrict__ deg, int* __restrict__ cnt) {
    int e = blockIdx.x * 256 + threadIdx.x;
    if (e >= NEDGES) return;
    __hip_atomic_fetch_add(&deg[src[e]], ew[e], __ATOMIC_RELAXED, __HIP_MEMORY_SCOPE_AGENT);
    __hip_atomic_fetch_add(&cnt[dst[e]], 1, __ATOMIC_RELAXED, __HIP_MEMORY_SCOPE_AGENT);
}

__global__ __launch_bounds__(256) void dinv_k(const float* __restrict__ deg, float* __restrict__ dinv) {
    int n = blockIdx.x * 256 + threadIdx.x;
    if (n >= NNODES) return;
    float d = deg[n];
    dinv[n] = (d > 0.f) ? rsqrtf(fmaxf(d, 1e-12f)) : 0.f;
}

// ---------------- exclusive scan (3-kernel) ----------------
__global__ __launch_bounds__(256) void scan1_k(const int* __restrict__ cnt, int* __restrict__ scanned,
                                               int* __restrict__ bsums, int n) {
    __shared__ int sm[256];
    int tid = threadIdx.x;
    int i = blockIdx.x * 256 + tid;
    int v = (i < n) ? cnt[i] : 0;
    sm[tid] = v;
    __syncthreads();
    #pragma unroll
    for (int off = 1; off < 256; off <<= 1) {
        int t = (tid >= off) ? sm[tid - off] : 0;
        __syncthreads();
        if (tid >= off) sm[tid] += t;
        __syncthreads();
    }
    if (i < n) scanned[i] = sm[tid] - v;          // exclusive
    if (tid == 255) bsums[blockIdx.x] = sm[255];  // block total
}

// parallel one-block scan of block sums (nb <= 512)
__global__ __launch_bounds__(512) void scan2_k(int* __restrict__ bsums, int nb) {
    __shared__ int sm[512];
    int t = threadIdx.x;
    int v = (t < nb) ? bsums[t] : 0;
    sm[t] = v;
    __syncthreads();
    #pragma unroll
    for (int off = 1; off < 512; off <<= 1) {
        int u = (t >= off) ? sm[t - off] : 0;
        __syncthreads();
        sm[t] += u;
        __syncthreads();
    }
    if (t < nb) bsums[t] = sm[t] - v;  // exclusive
}

__global__ __launch_bounds__(256) void scan3_k(const int* __restrict__ scanned, const int* __restrict__ bsums,
                                               int* __restrict__ rowptr, int* __restrict__ fillp, int n, int e) {
    int i = blockIdx.x * 256 + threadIdx.x;
    if (i < n) {
        int r = scanned[i] + bsums[blockIdx.x];
        rowptr[i] = r;
        fillp[i] = r;
    }
    if (i == 0) rowptr[n] = e;
}

// ---------------- CSR fill (by dst), packed (src, norm_w) ----------------
__global__ __launch_bounds__(256) void fill_k(const int* __restrict__ src, const int* __restrict__ dst,
                                              const float* __restrict__ ew, const float* __restrict__ dinv,
                                              int* __restrict__ fillp, int2* __restrict__ csr) {
    int e = blockIdx.x * 256 + threadIdx.x;
    if (e >= NEDGES) return;
    int s = src[e], d = dst[e];
    float nw = -dinv[s] * ew[e] * dinv[d];
    int pos = atomicAdd(&fillp[d], 1);
    csr[pos] = make_int2(s, __float_as_int(nw));
}

// ---------------- layer 1: gather + dense (64->64) + relu + fused y = h @ W2_1 ----------------
// one wave per node; 4 nodes per 256-thread block; no cross-wave sync needed
__global__ __launch_bounds__(256, 8) void layer1_k(const float* __restrict__ feat,
                                                   const int* __restrict__ rowptr,
                                                   const int2* __restrict__ csr,
                                                   const float* __restrict__ W0, const float* __restrict__ W1,
                                                   const float* __restrict__ b,
                                                   const float* __restrict__ W2_1,
                                                   float* __restrict__ hout, float* __restrict__ yout) {
    __shared__ float tx[4][192];
    int wid = threadIdx.x >> 6;
    int lane = threadIdx.x & 63;
    int n = blockIdx.x * 4 + wid;   // grid = 25000 -> exactly NNODES

    int rs = __builtin_amdgcn_readfirstlane(rowptr[n]);
    int re = __builtin_amdgcn_readfirstlane(rowptr[n + 1]);

    float tx0 = feat[n * 64 + lane];

    // gather: 4 independent accumulator chains -> 4 outstanding 256B row fetches
    float a0 = 0.f, a1 = 0.f, a2 = 0.f, a3 = 0.f;
    int i = rs;
    for (; i + 4 <= re; i += 4) {
        int2 p0 = csr[i], p1 = csr[i + 1], p2 = csr[i + 2], p3 = csr[i + 3];
        a0 = fmaf(asf(p0.y), feat[p0.x * 64 + lane], a0);
        a1 = fmaf(asf(p1.y), feat[p1.x * 64 + lane], a1);
        a2 = fmaf(asf(p2.y), feat[p2.x * 64 + lane], a2);
        a3 = fmaf(asf(p3.y), feat[p3.x * 64 + lane], a3);
    }
    for (; i < re; ++i) {
        int2 p = csr[i];
        a0 = fmaf(asf(p.y), feat[p.x * 64 + lane], a0);
    }
    float acc = (a0 + a1) + (a2 + a3);

    tx[wid][lane] = tx0;
    tx[wid][64 + lane] = acc;
    // wave-private LDS slice: no __syncthreads needed (compiler orders via lgkmcnt)

    // dense: h_j = b_j + sum_d tx0[d] W0[d][j] + acc[d] W1[d][j]
    // weight reads are fully coalesced (lane j reads column j) and L1-resident (2x16KB)
    float hj = b[lane];
    const float4* tp = (const float4*)&tx[wid][0];
    #pragma unroll
    for (int q = 0; q < 16; q++) {
        float4 a = tp[q];
        hj = fmaf(a.x, W0[(4 * q + 0) * 64 + lane], hj);
        hj = fmaf(a.y, W0[(4 * q + 1) * 64 + lane], hj);
        hj = fmaf(a.z, W0[(4 * q + 2) * 64 + lane], hj);
        hj = fmaf(a.w, W0[(4 * q + 3) * 64 + lane], hj);
    }
    #pragma unroll
    for (int q = 0; q < 16; q++) {
        float4 a = tp[16 + q];
        hj = fmaf(a.x, W1[(4 * q + 0) * 64 + lane], hj);
        hj = fmaf(a.y, W1[(4 * q + 1) * 64 + lane], hj);
        hj = fmaf(a.z, W1[(4 * q + 2) * 64 + lane], hj);
        hj = fmaf(a.w, W1[(4 * q + 3) * 64 + lane], hj);
    }
    float h = fmaxf(hj, 0.f);
    hout[n * 64 + lane] = h;

    // fused y = h @ W2_1  (100000 x 16): lets layer2 gather 16-wide rows (4x less traffic)
    tx[wid][128 + lane] = h;
    int j = lane & 15;
    int g = lane >> 4;
    float p = 0.f;
    #pragma unroll
    for (int t2 = 0; t2 < 16; t2++) {
        int d = g * 16 + t2;
        p = fmaf(tx[wid][128 + d], W2_1[d * 16 + j], p);
    }
    p += __shfl_xor(p, 16, 64);
    p += __shfl_xor(p, 32, 64);
    if (g == 0) yout[n * 16 + j] = p;
}

// ---------------- layer 2: 16-wide gather of y + dense h@W2_0 + log_softmax ----------------
// 4 edges processed per wave-instruction (16 lanes each), 2 accumulator chains
__global__ __launch_bounds__(256, 8) void layer2_k(const float* __restrict__ h,
                                                   const float* __restrict__ y,
                                                   const int* __restrict__ rowptr,
                                                   const int2* __restrict__ csr,
                                                   const float* __restrict__ W0, const float* __restrict__ b,
                                                   float* __restrict__ out) {
    __shared__ float hs[4][64];
    int wid = threadIdx.x >> 6;
    int lane = threadIdx.x & 63;
    int n = blockIdx.x * 4 + wid;

    int rs = __builtin_amdgcn_readfirstlane(rowptr[n]);
    int re = __builtin_amdgcn_readfirstlane(rowptr[n + 1]);

    hs[wid][lane] = h[n * 64 + lane];

    int j = lane & 15;
    int g = lane >> 4;   // group g handles edges rs+g, rs+g+4, rs+g+8, ...

    float a0 = 0.f, a1 = 0.f;
    int i = rs + g;
    for (; i + 4 < re; i += 8) {
        int2 p0 = csr[i], p1 = csr[i + 4];
        a0 = fmaf(asf(p0.y), y[p0.x * 16 + j], a0);
        a1 = fmaf(asf(p1.y), y[p1.x * 16 + j], a1);
    }
    if (i < re) {
        int2 p = csr[i];
        a0 = fmaf(asf(p.y), y[p.x * 16 + j], a0);
    }
    float part = a0 + a1;

    // dense partial: group g covers d in [16g, 16g+16)
    #pragma unroll
    for (int t2 = 0; t2 < 16; t2++) {
        int d = g * 16 + t2;
        part = fmaf(hs[wid][d], W0[d * 16 + j], part);
    }
    // combine gather partials + dense partials across the 4 groups
    part += __shfl_xor(part, 16, 64);
    part += __shfl_xor(part, 32, 64);
    float oc = part + b[j];

    // log_softmax over 16 classes (within each 16-lane group)
    float m = oc;
    #pragma unroll
    for (int mk = 1; mk < 16; mk <<= 1) m = fmaxf(m, __shfl_xor(m, mk, 64));
    float ex = expf(oc - m);
    float s = ex;
    #pragma unroll
    for (int mk = 1; mk < 16; mk <<= 1) s += __shfl_xor(s, mk, 64);
    float r = oc - m - logf(s);
    if (g == 0) out[n * 16 + j] = r;
}

extern "C" void kernel_launch(void* const* d_in, const int* in_sizes, int n_in,
                              void* d_out, int out_size, void* d_ws, size_t ws_size,
                              hipStream_t stream) {
    const float* feat = (const float*)d_in[0];
    const int*   eidx = (const int*)d_in[1];
    const float* ew   = (const float*)d_in[2];
    const float* W1_0 = (const float*)d_in[3];
    const float* W1_1 = (const float*)d_in[4];
    const float* b1   = (const float*)d_in[5];
    const float* W2_0 = (const float*)d_in[6];
    const float* W2_1 = (const float*)d_in[7];
    const float* b2   = (const float*)d_in[8];
    float* out = (float*)d_out;

    const int* srcv = eidx;            // edge_index[0]
    const int* dstv = eidx + NEDGES;   // edge_index[1]

    // workspace carve (4-byte elements; csr kept 8B-aligned)
    float* deg     = (float*)d_ws;                 // N
    float* dinv    = deg + NNODES;                 // N
    int*   cnt     = (int*)(dinv + NNODES);        // N
    int*   scanned = cnt + NNODES;                 // N
    int*   rowptr  = scanned + NNODES;             // N+1
    int*   fillp   = rowptr + NNODES + 1;          // N
    int*   bsums   = fillp + NNODES;               // 512 (+1 pad -> even offset)
    int2*  csr     = (int2*)(bsums + 512 + 1);     // E int2
    float* hbuf    = (float*)(csr + NEDGES);       // N*64
    float* ybuf    = hbuf + NNODES * 64;           // N*16

    hipMemsetAsync(deg, 0, NNODES * sizeof(float), stream);
    hipMemsetAsync(cnt, 0, NNODES * sizeof(int), stream);

    const int EB = (NEDGES + 255) / 256;     // 6250
    const int NB = (NNODES + 255) / 256;     // 391

    deg_hist_k<<<EB, 256, 0, stream>>>(srcv, dstv, ew, deg, cnt);
    dinv_k<<<NB, 256, 0, stream>>>(deg, dinv);
    scan1_k<<<NB, 256, 0, stream>>>(cnt, scanned, bsums, NNODES);
    scan2_k<<<1, 512, 0, stream>>>(bsums, NB);
    scan3_k<<<NB, 256, 0, stream>>>(scanned, bsums, rowptr, fillp, NNODES, NEDGES);
    fill_k<<<EB, 256, 0, stream>>>(srcv, dstv, ew, dinv, fillp, csr);

    layer1_k<<<NNODES / 4, 256, 0, stream>>>(feat, rowptr, csr, W1_0, W1_1, b1, W2_1, hbuf, ybuf);
    layer2_k<<<NNODES / 4, 256, 0, stream>>>(hbuf, ybuf, rowptr, csr, W2_0, b2, out);
}